// Round 18
// baseline (224.951 us; speedup 1.0000x reference)
//
#include <hip/hip_runtime.h>
#include <hip/hip_bf16.h>

#define N_NODES 100000
#define N_EDGES 1600000
#define IN_DIM 128
#define HID_DIM 256
#define LN_EPS 1e-5f
#define NT32 (N_NODES / 32)   // 3125 32-row tiles, exact

// histogram geometry: packed 2x u16 bins, 4 slices
#define NCHUNK 32
#define CHUNK_E (N_EDGES / NCHUNK)     // 50000 edges/chunk (12500 int4, exact)
#define NSLICE 4
#define SLICE (N_NODES / NSLICE)       // 25000 nodes/slice
#define SLICE_W (SLICE / 2)            // 12500 packed u32 bins (50 KB LDS)
#define HBLK (NCHUNK * NSLICE)         // 128 blocks per histogrammed array

#define EDGE_BLOCKS (N_EDGES / 256)       // 6250, exact
#define FCVT_BLOCKS (N_NODES * 32 / 256)  // 12500, exact

typedef short bf16x8 __attribute__((ext_vector_type(8)));
typedef float f32x4  __attribute__((ext_vector_type(4)));

static __device__ __forceinline__ short f2bf(float x) {
    return __builtin_bit_cast(short, __float2bfloat16(x));  // RNE round
}
static __device__ __forceinline__ float bf2f_lo(unsigned v) {
    return __builtin_bit_cast(float, v << 16);
}
static __device__ __forceinline__ float bf2f_hi(unsigned v) {
    return __builtin_bit_cast(float, v & 0xffff0000u);
}

// ---------------------------------------------------------------------------
// Kernel 1: LDS-bin histograms, packed 2 nodes per u32 (u16 fields).
// ---------------------------------------------------------------------------
__global__ __launch_bounds__(1024)
void hist_kernel(const int* __restrict__ src, const int* __restrict__ dst,
                 ushort* __restrict__ p_out16, ushort* __restrict__ p_in16,
                 ushort* __restrict__ rank16) {
    __shared__ unsigned bins[SLICE_W];   // 50 KB
    const int b = blockIdx.x;
    const bool isdst = (b >= HBLK);
    const int bb = isdst ? (b - HBLK) : b;
    const int ci = bb >> 2;            // chunk 0..31
    const int si = bb & 3;             // slice 0..3
    const int s0 = si * SLICE;

    for (int i = threadIdx.x; i < SLICE_W; i += 1024) bins[i] = 0;
    __syncthreads();

    const int4* ep4 = (const int4*)((isdst ? dst : src) + ci * CHUNK_E);
    if (isdst) {
        const int ebase = ci * CHUNK_E;
        for (int i = threadIdx.x; i < CHUNK_E / 4; i += 1024) {
            int4 v = ep4[i];
            int e0 = ebase + i * 4;
            unsigned u0 = (unsigned)(v.x - s0);
            unsigned u1 = (unsigned)(v.y - s0);
            unsigned u2 = (unsigned)(v.z - s0);
            unsigned u3 = (unsigned)(v.w - s0);
            if (u0 < SLICE) {
                unsigned sh = (u0 & 1) * 16;
                rank16[e0 + 0] = (ushort)(atomicAdd(&bins[u0 >> 1], 1u << sh) >> sh);
            }
            if (u1 < SLICE) {
                unsigned sh = (u1 & 1) * 16;
                rank16[e0 + 1] = (ushort)(atomicAdd(&bins[u1 >> 1], 1u << sh) >> sh);
            }
            if (u2 < SLICE) {
                unsigned sh = (u2 & 1) * 16;
                rank16[e0 + 2] = (ushort)(atomicAdd(&bins[u2 >> 1], 1u << sh) >> sh);
            }
            if (u3 < SLICE) {
                unsigned sh = (u3 & 1) * 16;
                rank16[e0 + 3] = (ushort)(atomicAdd(&bins[u3 >> 1], 1u << sh) >> sh);
            }
        }
    } else {
        for (int i = threadIdx.x; i < CHUNK_E / 4; i += 1024) {
            int4 v = ep4[i];
            unsigned u0 = (unsigned)(v.x - s0);
            unsigned u1 = (unsigned)(v.y - s0);
            unsigned u2 = (unsigned)(v.z - s0);
            unsigned u3 = (unsigned)(v.w - s0);
            if (u0 < SLICE) atomicAdd(&bins[u0 >> 1], 1u << ((u0 & 1) * 16));
            if (u1 < SLICE) atomicAdd(&bins[u1 >> 1], 1u << ((u1 & 1) * 16));
            if (u2 < SLICE) atomicAdd(&bins[u2 >> 1], 1u << ((u2 & 1) * 16));
            if (u3 < SLICE) atomicAdd(&bins[u3 >> 1], 1u << ((u3 & 1) * 16));
        }
    }
    __syncthreads();

    unsigned* pp = (unsigned*)((isdst ? p_in16 : p_out16) + (size_t)ci * N_NODES + s0);
    for (int i = threadIdx.x; i < SLICE_W; i += 1024) pp[i] = bins[i];
}

// ---------------------------------------------------------------------------
// Kernel 2: per-node: nsrc = rsqrt(max(deg_out,1)); exclusive prefix of
// p_in16 over chunks (in place) -> deg_in.
// ---------------------------------------------------------------------------
__global__ __launch_bounds__(256)
void prefix_kernel(const ushort* __restrict__ p_out16, ushort* __restrict__ p_in16,
                   float* __restrict__ nsrc, unsigned* __restrict__ deg_in) {
    int n = blockIdx.x * 256 + threadIdx.x;
    if (n >= N_NODES) return;
    unsigned so = 0;
    #pragma unroll
    for (int c = 0; c < NCHUNK; ++c) so += p_out16[(size_t)c * N_NODES + n];
    nsrc[n] = rsqrtf(fmaxf((float)so, 1.f));
    unsigned run = 0;
    #pragma unroll
    for (int c = 0; c < NCHUNK; ++c) {
        unsigned t = p_in16[(size_t)c * N_NODES + n];
        p_in16[(size_t)c * N_NODES + n] = (ushort)run;
        run += t;
    }
    deg_in[n] = run;
}

// ---------------------------------------------------------------------------
// Kernel 3: W / skipW -> bf16 MFMA B-fragment-major; + params table
// ---------------------------------------------------------------------------
__global__ void wcvt_kernel(const float* __restrict__ W, const float* __restrict__ sW,
                            const float* __restrict__ bvec, const float* __restrict__ gamma,
                            const float* __restrict__ beta, const float* __restrict__ skipb,
                            ushort* __restrict__ Wfrag, ushort* __restrict__ sWfrag,
                            float4* __restrict__ params) {
    int tid = blockIdx.x * blockDim.x + threadIdx.x;
    if (tid >= 8448) return;
    if (tid >= 8192) {
        int i = tid - 8192;   // 0..255
        params[i] = make_float4(bvec[i], gamma[i], beta[i], skipb[i]);
        return;
    }
    const float* srcm = (tid < 4096) ? W : sW;
    ushort* dstm = (tid < 4096) ? Wfrag : sWfrag;
    int u = tid & 4095;
    int lane = u & 63;
    int ks = (u >> 6) & 3;
    int n = u >> 8;
    int c = lane & 15, g = lane >> 4;
    int col = n * 16 + c;
    int k0 = ks * 32 + g * 8;
    ushort4 lo, hi;
    lo.x = (ushort)f2bf(srcm[(size_t)(k0 + 0) * HID_DIM + col]);
    lo.y = (ushort)f2bf(srcm[(size_t)(k0 + 1) * HID_DIM + col]);
    lo.z = (ushort)f2bf(srcm[(size_t)(k0 + 2) * HID_DIM + col]);
    lo.w = (ushort)f2bf(srcm[(size_t)(k0 + 3) * HID_DIM + col]);
    hi.x = (ushort)f2bf(srcm[(size_t)(k0 + 4) * HID_DIM + col]);
    hi.y = (ushort)f2bf(srcm[(size_t)(k0 + 5) * HID_DIM + col]);
    hi.z = (ushort)f2bf(srcm[(size_t)(k0 + 6) * HID_DIM + col]);
    hi.w = (ushort)f2bf(srcm[(size_t)(k0 + 7) * HID_DIM + col]);
    *(ushort4*)(dstm + (size_t)u * 8)     = lo;
    *(ushort4*)(dstm + (size_t)u * 8 + 4) = hi;
}

// ---------------------------------------------------------------------------
// Kernel 4: single-block exclusive scan (4 elems/thread) deg_in -> row_ptr
// ---------------------------------------------------------------------------
__global__ __launch_bounds__(1024)
void scan_kernel(const unsigned* __restrict__ deg_in, unsigned* __restrict__ row_ptr) {
    __shared__ unsigned wsum[16];
    __shared__ unsigned carry_s;
    if (threadIdx.x == 0) carry_s = 0;
    __syncthreads();
    const int lane = threadIdx.x & 63;
    const int wid  = threadIdx.x >> 6;
    for (int base = 0; base < N_NODES; base += 4096) {
        int i0 = base + threadIdx.x * 4;
        unsigned d0 = 0, d1 = 0, d2 = 0, d3 = 0;
        if (i0 < N_NODES) {
            uint4 v = *(const uint4*)(deg_in + i0);
            d0 = v.x; d1 = v.y; d2 = v.z; d3 = v.w;
        }
        unsigned t = d0 + d1 + d2 + d3;
        unsigned x = t;
        #pragma unroll
        for (int d = 1; d < 64; d <<= 1) {
            unsigned tt = __shfl_up(x, d, 64);
            if (lane >= d) x += tt;
        }
        if (lane == 63) wsum[wid] = x;
        __syncthreads();
        if (threadIdx.x == 0) {
            unsigned run = carry_s;
            #pragma unroll
            for (int w = 0; w < 16; ++w) { unsigned tmp = wsum[w]; wsum[w] = run; run += tmp; }
            carry_s = run;
        }
        __syncthreads();
        if (i0 < N_NODES) {
            unsigned b = wsum[wid] + (x - t);
            uint4 rp;
            rp.x = b; rp.y = b + d0; rp.z = b + d0 + d1; rp.w = b + d0 + d1 + d2;
            *(uint4*)(row_ptr + i0) = rp;
        }
        __syncthreads();
    }
    if (threadIdx.x == 0) row_ptr[N_NODES] = carry_s;
}

// ---------------------------------------------------------------------------
// Kernel 5 (pre2), fused by block range:
//   [0, 6250)       : atomic-free CSR fill via chunk-prefix + within-chunk rank
//   [6250, 18750)   : featb = bf16(feat)
// ---------------------------------------------------------------------------
__global__ __launch_bounds__(256)
void pre2_kernel(const int* __restrict__ src, const int* __restrict__ dst,
                 const unsigned* __restrict__ row_ptr, const ushort* __restrict__ p_in16,
                 const ushort* __restrict__ rank16, unsigned* __restrict__ edge_src,
                 const float* __restrict__ feat, ushort* __restrict__ featb) {
    const int b = blockIdx.x;
    if (b < EDGE_BLOCKS) {
        int e = b * 256 + threadIdx.x;
        int d = dst[e];
        int c = e / CHUNK_E;
        unsigned pos = row_ptr[d] + (unsigned)p_in16[(size_t)c * N_NODES + d]
                     + (unsigned)rank16[e];
        edge_src[pos] = (unsigned)src[e];
    } else {
        int id = (b - EDGE_BLOCKS) * 256 + threadIdx.x;   // exact N_NODES*32
        float4 v = ((const float4*)feat)[id];
        ushort4 o;
        o.x = (ushort)f2bf(v.x);
        o.y = (ushort)f2bf(v.y);
        o.z = (ushort)f2bf(v.z);
        o.w = (ushort)f2bf(v.w);
        ((ushort4*)featb)[id] = o;
    }
}

// ---------------------------------------------------------------------------
// Kernel 6: SpMM v2 — HALF-WAVE (32-lane) per edge, dwordx2 row reads.
// Each wave processes 2 edges concurrently; unroll 8 pairs = 16 edges in
// flight per wave (2x miss parallelism of v1, half the load instructions).
// Cross-half combine via shfl_xor(32); half 0 stores the 256 B row.
// ---------------------------------------------------------------------------
__global__ __launch_bounds__(256)
void spmm_kernel(const ushort* __restrict__ featb, const float* __restrict__ nsrc,
                 const unsigned* __restrict__ row_ptr, const unsigned* __restrict__ edge_src,
                 unsigned* __restrict__ aggb_u32) {
    int gw = (blockIdx.x * 256 + threadIdx.x) >> 6;
    int lane = threadIdx.x & 63;
    if (gw >= N_NODES) return;
    const int hw  = lane >> 5;    // half-wave 0/1
    const int l32 = lane & 31;    // lane within half
    unsigned beg = row_ptr[gw], end = row_ptr[gw + 1];
    float a0 = 0.f, a1 = 0.f, a2 = 0.f, a3 = 0.f;
    unsigned e = beg;
    // main: 8 pairs = 16 edges in flight
    for (; e + 16 <= end; e += 16) {
        unsigned s[8];
        #pragma unroll
        for (int q = 0; q < 8; ++q) s[q] = edge_src[e + 2 * q + hw];
        float ns[8];
        #pragma unroll
        for (int q = 0; q < 8; ++q) ns[q] = nsrc[s[q]];
        uint2 v[8];
        #pragma unroll
        for (int q = 0; q < 8; ++q)
            v[q] = *(const uint2*)(featb + (size_t)s[q] * IN_DIM + 4 * l32);
        #pragma unroll
        for (int q = 0; q < 8; ++q) {
            a0 = fmaf(bf2f_lo(v[q].x), ns[q], a0);
            a1 = fmaf(bf2f_hi(v[q].x), ns[q], a1);
            a2 = fmaf(bf2f_lo(v[q].y), ns[q], a2);
            a3 = fmaf(bf2f_hi(v[q].y), ns[q], a3);
        }
    }
    // pair tail
    for (; e + 2 <= end; e += 2) {
        unsigned s = edge_src[e + hw];
        float ns = nsrc[s];
        uint2 v = *(const uint2*)(featb + (size_t)s * IN_DIM + 4 * l32);
        a0 = fmaf(bf2f_lo(v.x), ns, a0);
        a1 = fmaf(bf2f_hi(v.x), ns, a1);
        a2 = fmaf(bf2f_lo(v.y), ns, a2);
        a3 = fmaf(bf2f_hi(v.y), ns, a3);
    }
    // single tail (half 0 only)
    if (e < end && hw == 0) {
        unsigned s = edge_src[e];
        float ns = nsrc[s];
        uint2 v = *(const uint2*)(featb + (size_t)s * IN_DIM + 4 * l32);
        a0 = fmaf(bf2f_lo(v.x), ns, a0);
        a1 = fmaf(bf2f_hi(v.x), ns, a1);
        a2 = fmaf(bf2f_lo(v.y), ns, a2);
        a3 = fmaf(bf2f_hi(v.y), ns, a3);
    }
    // combine the two halves (same elements, different edges)
    a0 += __shfl_xor(a0, 32, 64);
    a1 += __shfl_xor(a1, 32, 64);
    a2 += __shfl_xor(a2, 32, 64);
    a3 += __shfl_xor(a3, 32, 64);
    if (hw == 0) {
        float nd = rsqrtf(fmaxf((float)(end - beg), 1.0f));
        uint2 o;
        o.x = (unsigned)(ushort)f2bf(a0 * nd) | ((unsigned)(ushort)f2bf(a1 * nd) << 16);
        o.y = (unsigned)(ushort)f2bf(a2 * nd) | ((unsigned)(ushort)f2bf(a3 * nd) << 16);
        *(uint2*)(aggb_u32 + (size_t)gw * (IN_DIM / 2) + 2 * l32) = o;
    }
}

// ---------------------------------------------------------------------------
// Kernel 7: FUSED GEMM1 + LN + ReLU + GEMM2 -> out, v8 (32-row tiles,
// occupancy-pinned, launch_bounds(256,4)).
// ---------------------------------------------------------------------------
__global__ __launch_bounds__(256, 4)
void gemm_fused_kernel(const ushort* __restrict__ aggb, const ushort* __restrict__ featb,
                       const ushort* __restrict__ Wfrag, const ushort* __restrict__ sWfrag,
                       const float4* __restrict__ params, float* __restrict__ out) {
    __shared__ float2 red[4][32];      // [col-quarter][row-in-tile]: (s1,s2)
    const int tid = threadIdx.x;
    const int lane = tid & 63;
    const int h = tid >> 6;            // col-quarter 0..3
    const int c = lane & 15, g = lane >> 4;
    const int r0 = blockIdx.x * 32;    // tile base row
    const int n0 = h * 4;

    bf16x8 A[2][4];
    #pragma unroll
    for (int rg = 0; rg < 2; ++rg)
        #pragma unroll
        for (int ks = 0; ks < 4; ++ks)
            A[rg][ks] = *(const bf16x8*)(aggb + (size_t)(r0 + rg * 16 + c) * IN_DIM
                                         + ks * 32 + g * 8);

    f32x4 acc[2][4];
    #pragma unroll
    for (int i = 0; i < 4; ++i) {
        float bb = params[(n0 + i) * 16 + c].x;
        acc[0][i] = (f32x4){bb, bb, bb, bb};
        acc[1][i] = (f32x4){bb, bb, bb, bb};
        #pragma unroll
        for (int ks = 0; ks < 4; ++ks) {
            bf16x8 b = *(const bf16x8*)(Wfrag + (((n0 + i) * 4 + ks) * 64 + lane) * 8);
            acc[0][i] = __builtin_amdgcn_mfma_f32_16x16x32_bf16(A[0][ks], b, acc[0][i], 0, 0, 0);
            acc[1][i] = __builtin_amdgcn_mfma_f32_16x16x32_bf16(A[1][ks], b, acc[1][i], 0, 0, 0);
        }
    }

    #pragma unroll
    for (int rg = 0; rg < 2; ++rg)
        #pragma unroll
        for (int ks = 0; ks < 4; ++ks)
            A[rg][ks] = *(const bf16x8*)(featb + (size_t)(r0 + rg * 16 + c) * IN_DIM
                                         + ks * 32 + g * 8);

    {
        float s1[2][4], s2[2][4];
        #pragma unroll
        for (int rg = 0; rg < 2; ++rg)
            #pragma unroll
            for (int j = 0; j < 4; ++j) { s1[rg][j] = 0.f; s2[rg][j] = 0.f; }
        #pragma unroll
        for (int rg = 0; rg < 2; ++rg)
            #pragma unroll
            for (int i = 0; i < 4; ++i)
                #pragma unroll
                for (int j = 0; j < 4; ++j) {
                    s1[rg][j] += acc[rg][i][j];
                    s2[rg][j] = fmaf(acc[rg][i][j], acc[rg][i][j], s2[rg][j]);
                }
        #pragma unroll
        for (int m = 1; m <= 8; m <<= 1)
            #pragma unroll
            for (int rg = 0; rg < 2; ++rg)
                #pragma unroll
                for (int j = 0; j < 4; ++j) {
                    s1[rg][j] += __shfl_xor(s1[rg][j], m, 64);
                    s2[rg][j] += __shfl_xor(s2[rg][j], m, 64);
                }
        if (c == 0) {
            #pragma unroll
            for (int rg = 0; rg < 2; ++rg)
                #pragma unroll
                for (int j = 0; j < 4; ++j)
                    red[h][rg * 16 + g * 4 + j] = make_float2(s1[rg][j], s2[rg][j]);
        }
    }
    __syncthreads();

    float mu[2][4], rstd[2][4];
    #pragma unroll
    for (int rg = 0; rg < 2; ++rg)
        #pragma unroll
        for (int j = 0; j < 4; ++j) {
            int row = rg * 16 + g * 4 + j;
            float2 p0 = red[0][row];
            float2 p1 = red[1][row];
            float2 p2 = red[2][row];
            float2 p3 = red[3][row];
            float t1 = (p0.x + p1.x) + (p2.x + p3.x);
            float t2 = (p0.y + p1.y) + (p2.y + p3.y);
            mu[rg][j] = t1 * (1.f / HID_DIM);
            float var = t2 * (1.f / HID_DIM) - mu[rg][j] * mu[rg][j];
            rstd[rg][j] = rsqrtf(var + LN_EPS);
        }

    #pragma unroll
    for (int i = 0; i < 4; ++i) {
        float4 p = params[(n0 + i) * 16 + c];   // {b, gamma, beta, skipb}
        #pragma unroll
        for (int rg = 0; rg < 2; ++rg)
            #pragma unroll
            for (int j = 0; j < 4; ++j)
                acc[rg][i][j] = fmaxf(fmaf((acc[rg][i][j] - mu[rg][j]) * rstd[rg][j],
                                           p.y, p.z), 0.f) + p.w;
    }

    #pragma unroll
    for (int i = 0; i < 4; ++i) {
        #pragma unroll
        for (int ks = 0; ks < 4; ++ks) {
            bf16x8 b = *(const bf16x8*)(sWfrag + (((n0 + i) * 4 + ks) * 64 + lane) * 8);
            acc[0][i] = __builtin_amdgcn_mfma_f32_16x16x32_bf16(A[0][ks], b, acc[0][i], 0, 0, 0);
            acc[1][i] = __builtin_amdgcn_mfma_f32_16x16x32_bf16(A[1][ks], b, acc[1][i], 0, 0, 0);
        }
    }

    #pragma unroll
    for (int rg = 0; rg < 2; ++rg)
        #pragma unroll
        for (int i = 0; i < 4; ++i)
            #pragma unroll
            for (int j = 0; j < 4; ++j)
                out[(size_t)(r0 + rg * 16 + g * 4 + j) * HID_DIM + (n0 + i) * 16 + c]
                    = acc[rg][i][j];
}

// ---------------------------------------------------------------------------
extern "C" void kernel_launch(void* const* d_in, const int* in_sizes, int n_in,
                              void* d_out, int out_size, void* d_ws, size_t ws_size,
                              hipStream_t stream) {
    const float* feat  = (const float*)d_in[0];
    const int*   src   = (const int*)d_in[1];
    const int*   dst   = (const int*)d_in[2];
    const float* W     = (const float*)d_in[3];
    const float* bvec  = (const float*)d_in[4];
    const float* gamma = (const float*)d_in[5];
    const float* beta  = (const float*)d_in[6];
    const float* skipW = (const float*)d_in[7];
    const float* skipb = (const float*)d_in[8];
    float* out = (float*)d_out;

    // workspace, peak ≈ 70 MB (layout unchanged from round 17)
    char* ws = (char*)d_ws;
    ushort*   Wfrag    = (ushort*)ws;                               // 64 KB
    ushort*   sWfrag   = Wfrag + 32768;                             // 64 KB
    float4*   params   = (float4*)(sWfrag + 32768);                 // 4 KB
    ushort*   aggb     = (ushort*)(params + 256);                   // 25.6 MB
    char*     xbase    = (char*)(aggb + (size_t)N_NODES * IN_DIM);
    ushort*   featb    = (ushort*)xbase;                            // 25.6 MB
    ushort*   p_out16  = (ushort*)xbase;                            // 6.4 MB (alias featb)
    unsigned* edge_src = (unsigned*)(featb + (size_t)N_NODES * IN_DIM); // 6.4 MB
    ushort*   rank16   = (ushort*)(edge_src + N_EDGES);             // 3.2 MB
    ushort*   p_in16   = rank16 + N_EDGES;                          // 6.4 MB
    float*    nsrc     = (float*)(p_in16 + (size_t)NCHUNK * N_NODES); // 400 KB
    unsigned* deg_in   = (unsigned*)(nsrc + N_NODES);               // 400 KB
    unsigned* row_ptr  = deg_in + N_NODES;                          // 400 KB + pad

    wcvt_kernel<<<33, 256, 0, stream>>>(W, skipW, bvec, gamma, beta, skipb,
                                        Wfrag, sWfrag, params);

    hist_kernel<<<2 * HBLK, 1024, 0, stream>>>(src, dst, p_out16, p_in16, rank16);

    prefix_kernel<<<(N_NODES + 255) / 256, 256, 0, stream>>>(p_out16, p_in16, nsrc, deg_in);

    scan_kernel<<<1, 1024, 0, stream>>>(deg_in, row_ptr);

    pre2_kernel<<<EDGE_BLOCKS + FCVT_BLOCKS, 256, 0, stream>>>(
        src, dst, row_ptr, p_in16, rank16, edge_src, feat, featb);

    spmm_kernel<<<(N_NODES * 64 + 255) / 256, 256, 0, stream>>>(featb, nsrc, row_ptr,
                                                                edge_src, (unsigned*)aggb);

    gemm_fused_kernel<<<NT32, 256, 0, stream>>>(
        aggb, featb, Wfrag, sWfrag, params, out);
}

// Round 19
// 207.350 us; speedup vs baseline: 1.0849x; 1.0849x over previous
//
#include <hip/hip_runtime.h>
#include <hip/hip_bf16.h>

#define N_NODES 100000
#define N_EDGES 1600000
#define IN_DIM 128
#define HID_DIM 256
#define LN_EPS 1e-5f
#define NT32 (N_NODES / 32)   // 3125 32-row tiles, exact

// histogram geometry: packed 2x u16 bins, 4 slices
#define NCHUNK 32
#define CHUNK_E (N_EDGES / NCHUNK)     // 50000 edges/chunk (12500 int4, exact)
#define NSLICE 4
#define SLICE (N_NODES / NSLICE)       // 25000 nodes/slice
#define SLICE_W (SLICE / 2)            // 12500 packed u32 bins (50 KB LDS)
#define HBLK (NCHUNK * NSLICE)         // 128 blocks per histogrammed array
#define WCVT_BLKS 9                    // 9 x 1024 >= 8448 wcvt items

#define EDGE_BLOCKS (N_EDGES / 256)       // 6250, exact
#define FCVT_BLOCKS (N_NODES * 32 / 256)  // 12500, exact

typedef short bf16x8 __attribute__((ext_vector_type(8)));
typedef float f32x4  __attribute__((ext_vector_type(4)));

static __device__ __forceinline__ short f2bf(float x) {
    return __builtin_bit_cast(short, __float2bfloat16(x));  // RNE round
}
static __device__ __forceinline__ float bf2f_lo(unsigned v) {
    return __builtin_bit_cast(float, v << 16);
}
static __device__ __forceinline__ float bf2f_hi(unsigned v) {
    return __builtin_bit_cast(float, v & 0xffff0000u);
}

// ---------------------------------------------------------------------------
// Kernel 1 (hist + wcvt fused by block range):
//   [0, 128)    : histogram of src -> p_out16[chunk][node]
//   [128, 256)  : histogram of dst -> p_in16[chunk][node] + rank16[e]
//   [256, 265)  : W/skipW -> bf16 fragment-major + params table
// Packed 2 nodes per u32 bin (u16 fields); carry-safe (counts << 65536).
// ---------------------------------------------------------------------------
__global__ __launch_bounds__(1024)
void hist_kernel(const int* __restrict__ src, const int* __restrict__ dst,
                 ushort* __restrict__ p_out16, ushort* __restrict__ p_in16,
                 ushort* __restrict__ rank16,
                 const float* __restrict__ W, const float* __restrict__ sW,
                 const float* __restrict__ bvec, const float* __restrict__ gamma,
                 const float* __restrict__ beta, const float* __restrict__ skipb,
                 ushort* __restrict__ Wfrag, ushort* __restrict__ sWfrag,
                 float4* __restrict__ params) {
    __shared__ unsigned bins[SLICE_W];   // 50 KB
    const int b = blockIdx.x;
    if (b >= 2 * HBLK) {
        // ---- wcvt part ------------------------------------------------------
        int tid = (b - 2 * HBLK) * 1024 + threadIdx.x;
        if (tid >= 8448) return;
        if (tid >= 8192) {
            int i = tid - 8192;   // 0..255
            params[i] = make_float4(bvec[i], gamma[i], beta[i], skipb[i]);
            return;
        }
        const float* srcm = (tid < 4096) ? W : sW;
        ushort* dstm = (tid < 4096) ? Wfrag : sWfrag;
        int u = tid & 4095;
        int lane = u & 63;
        int ks = (u >> 6) & 3;
        int n = u >> 8;
        int c = lane & 15, g = lane >> 4;
        int col = n * 16 + c;
        int k0 = ks * 32 + g * 8;
        ushort4 lo, hi;
        lo.x = (ushort)f2bf(srcm[(size_t)(k0 + 0) * HID_DIM + col]);
        lo.y = (ushort)f2bf(srcm[(size_t)(k0 + 1) * HID_DIM + col]);
        lo.z = (ushort)f2bf(srcm[(size_t)(k0 + 2) * HID_DIM + col]);
        lo.w = (ushort)f2bf(srcm[(size_t)(k0 + 3) * HID_DIM + col]);
        hi.x = (ushort)f2bf(srcm[(size_t)(k0 + 4) * HID_DIM + col]);
        hi.y = (ushort)f2bf(srcm[(size_t)(k0 + 5) * HID_DIM + col]);
        hi.z = (ushort)f2bf(srcm[(size_t)(k0 + 6) * HID_DIM + col]);
        hi.w = (ushort)f2bf(srcm[(size_t)(k0 + 7) * HID_DIM + col]);
        *(ushort4*)(dstm + (size_t)u * 8)     = lo;
        *(ushort4*)(dstm + (size_t)u * 8 + 4) = hi;
        return;
    }
    const bool isdst = (b >= HBLK);
    const int bb = isdst ? (b - HBLK) : b;
    const int ci = bb >> 2;            // chunk 0..31
    const int si = bb & 3;             // slice 0..3
    const int s0 = si * SLICE;

    for (int i = threadIdx.x; i < SLICE_W; i += 1024) bins[i] = 0;
    __syncthreads();

    const int4* ep4 = (const int4*)((isdst ? dst : src) + ci * CHUNK_E);
    if (isdst) {
        const int ebase = ci * CHUNK_E;
        for (int i = threadIdx.x; i < CHUNK_E / 4; i += 1024) {
            int4 v = ep4[i];
            int e0 = ebase + i * 4;
            unsigned u0 = (unsigned)(v.x - s0);
            unsigned u1 = (unsigned)(v.y - s0);
            unsigned u2 = (unsigned)(v.z - s0);
            unsigned u3 = (unsigned)(v.w - s0);
            if (u0 < SLICE) {
                unsigned sh = (u0 & 1) * 16;
                rank16[e0 + 0] = (ushort)(atomicAdd(&bins[u0 >> 1], 1u << sh) >> sh);
            }
            if (u1 < SLICE) {
                unsigned sh = (u1 & 1) * 16;
                rank16[e0 + 1] = (ushort)(atomicAdd(&bins[u1 >> 1], 1u << sh) >> sh);
            }
            if (u2 < SLICE) {
                unsigned sh = (u2 & 1) * 16;
                rank16[e0 + 2] = (ushort)(atomicAdd(&bins[u2 >> 1], 1u << sh) >> sh);
            }
            if (u3 < SLICE) {
                unsigned sh = (u3 & 1) * 16;
                rank16[e0 + 3] = (ushort)(atomicAdd(&bins[u3 >> 1], 1u << sh) >> sh);
            }
        }
    } else {
        for (int i = threadIdx.x; i < CHUNK_E / 4; i += 1024) {
            int4 v = ep4[i];
            unsigned u0 = (unsigned)(v.x - s0);
            unsigned u1 = (unsigned)(v.y - s0);
            unsigned u2 = (unsigned)(v.z - s0);
            unsigned u3 = (unsigned)(v.w - s0);
            if (u0 < SLICE) atomicAdd(&bins[u0 >> 1], 1u << ((u0 & 1) * 16));
            if (u1 < SLICE) atomicAdd(&bins[u1 >> 1], 1u << ((u1 & 1) * 16));
            if (u2 < SLICE) atomicAdd(&bins[u2 >> 1], 1u << ((u2 & 1) * 16));
            if (u3 < SLICE) atomicAdd(&bins[u3 >> 1], 1u << ((u3 & 1) * 16));
        }
    }
    __syncthreads();

    unsigned* pp = (unsigned*)((isdst ? p_in16 : p_out16) + (size_t)ci * N_NODES + s0);
    for (int i = threadIdx.x; i < SLICE_W; i += 1024) pp[i] = bins[i];
}

// ---------------------------------------------------------------------------
// Kernel 2: per-node: nsrc = rsqrt(max(deg_out,1)); exclusive prefix of
// p_in16 over chunks (in place) -> deg_in.
// ---------------------------------------------------------------------------
__global__ __launch_bounds__(256)
void prefix_kernel(const ushort* __restrict__ p_out16, ushort* __restrict__ p_in16,
                   float* __restrict__ nsrc, unsigned* __restrict__ deg_in) {
    int n = blockIdx.x * 256 + threadIdx.x;
    if (n >= N_NODES) return;
    unsigned so = 0;
    #pragma unroll
    for (int c = 0; c < NCHUNK; ++c) so += p_out16[(size_t)c * N_NODES + n];
    nsrc[n] = rsqrtf(fmaxf((float)so, 1.f));
    unsigned run = 0;
    #pragma unroll
    for (int c = 0; c < NCHUNK; ++c) {
        unsigned t = p_in16[(size_t)c * N_NODES + n];
        p_in16[(size_t)c * N_NODES + n] = (ushort)run;
        run += t;
    }
    deg_in[n] = run;
}

// ---------------------------------------------------------------------------
// Kernel 3: single-block exclusive scan, 8 elems/thread (13 outer iters)
// ---------------------------------------------------------------------------
__global__ __launch_bounds__(1024)
void scan_kernel(const unsigned* __restrict__ deg_in, unsigned* __restrict__ row_ptr) {
    __shared__ unsigned wsum[16];
    __shared__ unsigned carry_s;
    if (threadIdx.x == 0) carry_s = 0;
    __syncthreads();
    const int lane = threadIdx.x & 63;
    const int wid  = threadIdx.x >> 6;
    for (int base = 0; base < N_NODES; base += 8192) {
        int i0 = base + threadIdx.x * 8;
        unsigned d[8];
        #pragma unroll
        for (int k = 0; k < 8; ++k) d[k] = 0;
        if (i0 < N_NODES) {   // N_NODES % 8 == 0 -> octet fully in-range
            uint4 v0 = *(const uint4*)(deg_in + i0);
            uint4 v1 = *(const uint4*)(deg_in + i0 + 4);
            d[0] = v0.x; d[1] = v0.y; d[2] = v0.z; d[3] = v0.w;
            d[4] = v1.x; d[5] = v1.y; d[6] = v1.z; d[7] = v1.w;
        }
        unsigned t = 0;
        #pragma unroll
        for (int k = 0; k < 8; ++k) t += d[k];
        unsigned x = t;
        #pragma unroll
        for (int dd = 1; dd < 64; dd <<= 1) {
            unsigned tt = __shfl_up(x, dd, 64);
            if (lane >= dd) x += tt;
        }
        if (lane == 63) wsum[wid] = x;
        __syncthreads();
        if (threadIdx.x == 0) {
            unsigned run = carry_s;
            #pragma unroll
            for (int w = 0; w < 16; ++w) { unsigned tmp = wsum[w]; wsum[w] = run; run += tmp; }
            carry_s = run;
        }
        __syncthreads();
        if (i0 < N_NODES) {
            unsigned bprefix = wsum[wid] + (x - t);
            unsigned rp[8];
            unsigned run = bprefix;
            #pragma unroll
            for (int k = 0; k < 8; ++k) { rp[k] = run; run += d[k]; }
            *(uint4*)(row_ptr + i0)     = make_uint4(rp[0], rp[1], rp[2], rp[3]);
            *(uint4*)(row_ptr + i0 + 4) = make_uint4(rp[4], rp[5], rp[6], rp[7]);
        }
        __syncthreads();
    }
    if (threadIdx.x == 0) row_ptr[N_NODES] = carry_s;
}

// ---------------------------------------------------------------------------
// Kernel 4 (pre2), fused by block range:
//   [0, 6250)       : atomic-free CSR fill via chunk-prefix + within-chunk rank
//   [6250, 18750)   : featb = bf16(feat)
// ---------------------------------------------------------------------------
__global__ __launch_bounds__(256)
void pre2_kernel(const int* __restrict__ src, const int* __restrict__ dst,
                 const unsigned* __restrict__ row_ptr, const ushort* __restrict__ p_in16,
                 const ushort* __restrict__ rank16, unsigned* __restrict__ edge_src,
                 const float* __restrict__ feat, ushort* __restrict__ featb) {
    const int b = blockIdx.x;
    if (b < EDGE_BLOCKS) {
        int e = b * 256 + threadIdx.x;
        int d = dst[e];
        int c = e / CHUNK_E;
        unsigned pos = row_ptr[d] + (unsigned)p_in16[(size_t)c * N_NODES + d]
                     + (unsigned)rank16[e];
        edge_src[pos] = (unsigned)src[e];
    } else {
        int id = (b - EDGE_BLOCKS) * 256 + threadIdx.x;   // exact N_NODES*32
        float4 v = ((const float4*)feat)[id];
        ushort4 o;
        o.x = (ushort)f2bf(v.x);
        o.y = (ushort)f2bf(v.y);
        o.z = (ushort)f2bf(v.z);
        o.w = (ushort)f2bf(v.w);
        ((ushort4*)featb)[id] = o;
    }
}

// ---------------------------------------------------------------------------
// Kernel 5: row-per-wave gather SpMM over bf16 featb, scale by nsrc[s] -> aggb
// (reverted to the proven full-wave, 8-deep-unroll structure)
// ---------------------------------------------------------------------------
__global__ __launch_bounds__(256)
void spmm_kernel(const ushort* __restrict__ featb, const float* __restrict__ nsrc,
                 const unsigned* __restrict__ row_ptr, const unsigned* __restrict__ edge_src,
                 unsigned* __restrict__ aggb_u32) {
    int gw = (blockIdx.x * 256 + threadIdx.x) >> 6;
    int lane = threadIdx.x & 63;
    if (gw >= N_NODES) return;
    unsigned beg = row_ptr[gw], end = row_ptr[gw + 1];
    float a0 = 0.f, a1 = 0.f;
    unsigned e = beg;
    for (; e + 8 <= end; e += 8) {
        unsigned s[8];
        #pragma unroll
        for (int q = 0; q < 8; ++q) s[q] = edge_src[e + q];
        float ns[8];
        #pragma unroll
        for (int q = 0; q < 8; ++q) ns[q] = nsrc[s[q]];
        unsigned v[8];
        #pragma unroll
        for (int q = 0; q < 8; ++q)
            v[q] = *(const unsigned*)(featb + (size_t)s[q] * IN_DIM + 2 * lane);
        #pragma unroll
        for (int q = 0; q < 8; ++q) {
            a0 = fmaf(bf2f_lo(v[q]), ns[q], a0);
            a1 = fmaf(bf2f_hi(v[q]), ns[q], a1);
        }
    }
    for (; e < end; ++e) {
        unsigned s = edge_src[e];
        float ns = nsrc[s];
        unsigned v = *(const unsigned*)(featb + (size_t)s * IN_DIM + 2 * lane);
        a0 = fmaf(bf2f_lo(v), ns, a0); a1 = fmaf(bf2f_hi(v), ns, a1);
    }
    float nd = rsqrtf(fmaxf((float)(end - beg), 1.0f));
    unsigned lo = (unsigned)(ushort)f2bf(a0 * nd);
    unsigned hi = (unsigned)(ushort)f2bf(a1 * nd);
    aggb_u32[(size_t)gw * (IN_DIM / 2) + lane] = lo | (hi << 16);
}

// ---------------------------------------------------------------------------
// Kernel 6: FUSED GEMM1 + LN + ReLU + GEMM2 -> out, v8 (32-row tiles,
// occupancy-pinned, launch_bounds(256,4)) — unchanged from round 17.
// ---------------------------------------------------------------------------
__global__ __launch_bounds__(256, 4)
void gemm_fused_kernel(const ushort* __restrict__ aggb, const ushort* __restrict__ featb,
                       const ushort* __restrict__ Wfrag, const ushort* __restrict__ sWfrag,
                       const float4* __restrict__ params, float* __restrict__ out) {
    __shared__ float2 red[4][32];      // [col-quarter][row-in-tile]: (s1,s2)
    const int tid = threadIdx.x;
    const int lane = tid & 63;
    const int h = tid >> 6;            // col-quarter 0..3
    const int c = lane & 15, g = lane >> 4;
    const int r0 = blockIdx.x * 32;    // tile base row
    const int n0 = h * 4;

    bf16x8 A[2][4];
    #pragma unroll
    for (int rg = 0; rg < 2; ++rg)
        #pragma unroll
        for (int ks = 0; ks < 4; ++ks)
            A[rg][ks] = *(const bf16x8*)(aggb + (size_t)(r0 + rg * 16 + c) * IN_DIM
                                         + ks * 32 + g * 8);

    f32x4 acc[2][4];
    #pragma unroll
    for (int i = 0; i < 4; ++i) {
        float bb = params[(n0 + i) * 16 + c].x;
        acc[0][i] = (f32x4){bb, bb, bb, bb};
        acc[1][i] = (f32x4){bb, bb, bb, bb};
        #pragma unroll
        for (int ks = 0; ks < 4; ++ks) {
            bf16x8 b = *(const bf16x8*)(Wfrag + (((n0 + i) * 4 + ks) * 64 + lane) * 8);
            acc[0][i] = __builtin_amdgcn_mfma_f32_16x16x32_bf16(A[0][ks], b, acc[0][i], 0, 0, 0);
            acc[1][i] = __builtin_amdgcn_mfma_f32_16x16x32_bf16(A[1][ks], b, acc[1][i], 0, 0, 0);
        }
    }

    #pragma unroll
    for (int rg = 0; rg < 2; ++rg)
        #pragma unroll
        for (int ks = 0; ks < 4; ++ks)
            A[rg][ks] = *(const bf16x8*)(featb + (size_t)(r0 + rg * 16 + c) * IN_DIM
                                         + ks * 32 + g * 8);

    {
        float s1[2][4], s2[2][4];
        #pragma unroll
        for (int rg = 0; rg < 2; ++rg)
            #pragma unroll
            for (int j = 0; j < 4; ++j) { s1[rg][j] = 0.f; s2[rg][j] = 0.f; }
        #pragma unroll
        for (int rg = 0; rg < 2; ++rg)
            #pragma unroll
            for (int i = 0; i < 4; ++i)
                #pragma unroll
                for (int j = 0; j < 4; ++j) {
                    s1[rg][j] += acc[rg][i][j];
                    s2[rg][j] = fmaf(acc[rg][i][j], acc[rg][i][j], s2[rg][j]);
                }
        #pragma unroll
        for (int m = 1; m <= 8; m <<= 1)
            #pragma unroll
            for (int rg = 0; rg < 2; ++rg)
                #pragma unroll
                for (int j = 0; j < 4; ++j) {
                    s1[rg][j] += __shfl_xor(s1[rg][j], m, 64);
                    s2[rg][j] += __shfl_xor(s2[rg][j], m, 64);
                }
        if (c == 0) {
            #pragma unroll
            for (int rg = 0; rg < 2; ++rg)
                #pragma unroll
                for (int j = 0; j < 4; ++j)
                    red[h][rg * 16 + g * 4 + j] = make_float2(s1[rg][j], s2[rg][j]);
        }
    }
    __syncthreads();

    float mu[2][4], rstd[2][4];
    #pragma unroll
    for (int rg = 0; rg < 2; ++rg)
        #pragma unroll
        for (int j = 0; j < 4; ++j) {
            int row = rg * 16 + g * 4 + j;
            float2 p0 = red[0][row];
            float2 p1 = red[1][row];
            float2 p2 = red[2][row];
            float2 p3 = red[3][row];
            float t1 = (p0.x + p1.x) + (p2.x + p3.x);
            float t2 = (p0.y + p1.y) + (p2.y + p3.y);
            mu[rg][j] = t1 * (1.f / HID_DIM);
            float var = t2 * (1.f / HID_DIM) - mu[rg][j] * mu[rg][j];
            rstd[rg][j] = rsqrtf(var + LN_EPS);
        }

    #pragma unroll
    for (int i = 0; i < 4; ++i) {
        float4 p = params[(n0 + i) * 16 + c];   // {b, gamma, beta, skipb}
        #pragma unroll
        for (int rg = 0; rg < 2; ++rg)
            #pragma unroll
            for (int j = 0; j < 4; ++j)
                acc[rg][i][j] = fmaxf(fmaf((acc[rg][i][j] - mu[rg][j]) * rstd[rg][j],
                                           p.y, p.z), 0.f) + p.w;
    }

    #pragma unroll
    for (int i = 0; i < 4; ++i) {
        #pragma unroll
        for (int ks = 0; ks < 4; ++ks) {
            bf16x8 b = *(const bf16x8*)(sWfrag + (((n0 + i) * 4 + ks) * 64 + lane) * 8);
            acc[0][i] = __builtin_amdgcn_mfma_f32_16x16x32_bf16(A[0][ks], b, acc[0][i], 0, 0, 0);
            acc[1][i] = __builtin_amdgcn_mfma_f32_16x16x32_bf16(A[1][ks], b, acc[1][i], 0, 0, 0);
        }
    }

    #pragma unroll
    for (int rg = 0; rg < 2; ++rg)
        #pragma unroll
        for (int i = 0; i < 4; ++i)
            #pragma unroll
            for (int j = 0; j < 4; ++j)
                out[(size_t)(r0 + rg * 16 + g * 4 + j) * HID_DIM + (n0 + i) * 16 + c]
                    = acc[rg][i][j];
}

// ---------------------------------------------------------------------------
extern "C" void kernel_launch(void* const* d_in, const int* in_sizes, int n_in,
                              void* d_out, int out_size, void* d_ws, size_t ws_size,
                              hipStream_t stream) {
    const float* feat  = (const float*)d_in[0];
    const int*   src   = (const int*)d_in[1];
    const int*   dst   = (const int*)d_in[2];
    const float* W     = (const float*)d_in[3];
    const float* bvec  = (const float*)d_in[4];
    const float* gamma = (const float*)d_in[5];
    const float* beta  = (const float*)d_in[6];
    const float* skipW = (const float*)d_in[7];
    const float* skipb = (const float*)d_in[8];
    float* out = (float*)d_out;

    // workspace, peak ≈ 70 MB (layout unchanged)
    char* ws = (char*)d_ws;
    ushort*   Wfrag    = (ushort*)ws;                               // 64 KB
    ushort*   sWfrag   = Wfrag + 32768;                             // 64 KB
    float4*   params   = (float4*)(sWfrag + 32768);                 // 4 KB
    ushort*   aggb     = (ushort*)(params + 256);                   // 25.6 MB
    char*     xbase    = (char*)(aggb + (size_t)N_NODES * IN_DIM);
    ushort*   featb    = (ushort*)xbase;                            // 25.6 MB
    ushort*   p_out16  = (ushort*)xbase;                            // 6.4 MB (alias featb)
    unsigned* edge_src = (unsigned*)(featb + (size_t)N_NODES * IN_DIM); // 6.4 MB
    ushort*   rank16   = (ushort*)(edge_src + N_EDGES);             // 3.2 MB
    ushort*   p_in16   = rank16 + N_EDGES;                          // 6.4 MB
    float*    nsrc     = (float*)(p_in16 + (size_t)NCHUNK * N_NODES); // 400 KB
    unsigned* deg_in   = (unsigned*)(nsrc + N_NODES);               // 400 KB
    unsigned* row_ptr  = deg_in + N_NODES;                          // 400 KB + pad

    hist_kernel<<<2 * HBLK + WCVT_BLKS, 1024, 0, stream>>>(
        src, dst, p_out16, p_in16, rank16,
        W, skipW, bvec, gamma, beta, skipb, Wfrag, sWfrag, params);

    prefix_kernel<<<(N_NODES + 255) / 256, 256, 0, stream>>>(p_out16, p_in16, nsrc, deg_in);

    scan_kernel<<<1, 1024, 0, stream>>>(deg_in, row_ptr);

    pre2_kernel<<<EDGE_BLOCKS + FCVT_BLOCKS, 256, 0, stream>>>(
        src, dst, row_ptr, p_in16, rank16, edge_src, feat, featb);

    spmm_kernel<<<(N_NODES * 64 + 255) / 256, 256, 0, stream>>>(featb, nsrc, row_ptr,
                                                                edge_src, (unsigned*)aggb);

    gemm_fused_kernel<<<NT32, 256, 0, stream>>>(
        aggb, featb, Wfrag, sWfrag, params, out);
}

// Round 20
// 206.556 us; speedup vs baseline: 1.0891x; 1.0038x over previous
//
#include <hip/hip_runtime.h>
#include <hip/hip_bf16.h>

#define N_NODES 100000
#define N_EDGES 1600000
#define IN_DIM 128
#define HID_DIM 256
#define LN_EPS 1e-5f
#define NT32 (N_NODES / 32)   // 3125 32-row tiles, exact

// histogram geometry: packed 2x u16 bins, 4 slices
#define NCHUNK 32
#define CHUNK_E (N_EDGES / NCHUNK)     // 50000 edges/chunk (12500 int4, exact)
#define NSLICE 4
#define SLICE (N_NODES / NSLICE)       // 25000 nodes/slice
#define SLICE_W (SLICE / 2)            // 12500 packed u32 bins (50 KB LDS)
#define HBLK (NCHUNK * NSLICE)         // 128 blocks per histogrammed array
#define WCVT_BLKS 9                    // 9 x 1024 >= 8448 wcvt items
#define FCVT_BLKS (N_NODES * 32 / 1024)  // 3125 blocks x 1024 thr, exact

#define EDGE_BLOCKS (N_EDGES / 256)       // 6250, exact

typedef short bf16x8 __attribute__((ext_vector_type(8)));
typedef float f32x4  __attribute__((ext_vector_type(4)));

static __device__ __forceinline__ short f2bf(float x) {
    return __builtin_bit_cast(short, __float2bfloat16(x));  // RNE round
}
static __device__ __forceinline__ float bf2f_lo(unsigned v) {
    return __builtin_bit_cast(float, v << 16);
}
static __device__ __forceinline__ float bf2f_hi(unsigned v) {
    return __builtin_bit_cast(float, v & 0xffff0000u);
}

// ---------------------------------------------------------------------------
// Kernel 1 (hist + wcvt + fcvt fused by block range):
//   [0, 128)        : histogram of src -> p_out16[chunk][node]
//   [128, 256)      : histogram of dst -> p_in16[chunk][node] + rank16[e]
//   [256, 265)      : W/skipW -> bf16 fragment-major + params table
//   [265, 265+3125) : featb = bf16(feat)  (independent streaming work,
//                     overlaps the latency-bound histogram blocks)
// ---------------------------------------------------------------------------
__global__ __launch_bounds__(1024)
void hist_kernel(const int* __restrict__ src, const int* __restrict__ dst,
                 ushort* __restrict__ p_out16, ushort* __restrict__ p_in16,
                 ushort* __restrict__ rank16,
                 const float* __restrict__ W, const float* __restrict__ sW,
                 const float* __restrict__ bvec, const float* __restrict__ gamma,
                 const float* __restrict__ beta, const float* __restrict__ skipb,
                 ushort* __restrict__ Wfrag, ushort* __restrict__ sWfrag,
                 float4* __restrict__ params,
                 const float* __restrict__ feat, ushort* __restrict__ featb) {
    __shared__ unsigned bins[SLICE_W];   // 50 KB
    const int b = blockIdx.x;
    if (b >= 2 * HBLK + WCVT_BLKS) {
        // ---- fcvt part: one float4 -> ushort4 per thread --------------------
        int id = (b - 2 * HBLK - WCVT_BLKS) * 1024 + threadIdx.x;  // exact N*32
        float4 v = ((const float4*)feat)[id];
        ushort4 o;
        o.x = (ushort)f2bf(v.x);
        o.y = (ushort)f2bf(v.y);
        o.z = (ushort)f2bf(v.z);
        o.w = (ushort)f2bf(v.w);
        ((ushort4*)featb)[id] = o;
        return;
    }
    if (b >= 2 * HBLK) {
        // ---- wcvt part ------------------------------------------------------
        int tid = (b - 2 * HBLK) * 1024 + threadIdx.x;
        if (tid >= 8448) return;
        if (tid >= 8192) {
            int i = tid - 8192;   // 0..255
            params[i] = make_float4(bvec[i], gamma[i], beta[i], skipb[i]);
            return;
        }
        const float* srcm = (tid < 4096) ? W : sW;
        ushort* dstm = (tid < 4096) ? Wfrag : sWfrag;
        int u = tid & 4095;
        int lane = u & 63;
        int ks = (u >> 6) & 3;
        int n = u >> 8;
        int c = lane & 15, g = lane >> 4;
        int col = n * 16 + c;
        int k0 = ks * 32 + g * 8;
        ushort4 lo, hi;
        lo.x = (ushort)f2bf(srcm[(size_t)(k0 + 0) * HID_DIM + col]);
        lo.y = (ushort)f2bf(srcm[(size_t)(k0 + 1) * HID_DIM + col]);
        lo.z = (ushort)f2bf(srcm[(size_t)(k0 + 2) * HID_DIM + col]);
        lo.w = (ushort)f2bf(srcm[(size_t)(k0 + 3) * HID_DIM + col]);
        hi.x = (ushort)f2bf(srcm[(size_t)(k0 + 4) * HID_DIM + col]);
        hi.y = (ushort)f2bf(srcm[(size_t)(k0 + 5) * HID_DIM + col]);
        hi.z = (ushort)f2bf(srcm[(size_t)(k0 + 6) * HID_DIM + col]);
        hi.w = (ushort)f2bf(srcm[(size_t)(k0 + 7) * HID_DIM + col]);
        *(ushort4*)(dstm + (size_t)u * 8)     = lo;
        *(ushort4*)(dstm + (size_t)u * 8 + 4) = hi;
        return;
    }
    const bool isdst = (b >= HBLK);
    const int bb = isdst ? (b - HBLK) : b;
    const int ci = bb >> 2;            // chunk 0..31
    const int si = bb & 3;             // slice 0..3
    const int s0 = si * SLICE;

    for (int i = threadIdx.x; i < SLICE_W; i += 1024) bins[i] = 0;
    __syncthreads();

    const int4* ep4 = (const int4*)((isdst ? dst : src) + ci * CHUNK_E);
    if (isdst) {
        const int ebase = ci * CHUNK_E;
        for (int i = threadIdx.x; i < CHUNK_E / 4; i += 1024) {
            int4 v = ep4[i];
            int e0 = ebase + i * 4;
            unsigned u0 = (unsigned)(v.x - s0);
            unsigned u1 = (unsigned)(v.y - s0);
            unsigned u2 = (unsigned)(v.z - s0);
            unsigned u3 = (unsigned)(v.w - s0);
            if (u0 < SLICE) {
                unsigned sh = (u0 & 1) * 16;
                rank16[e0 + 0] = (ushort)(atomicAdd(&bins[u0 >> 1], 1u << sh) >> sh);
            }
            if (u1 < SLICE) {
                unsigned sh = (u1 & 1) * 16;
                rank16[e0 + 1] = (ushort)(atomicAdd(&bins[u1 >> 1], 1u << sh) >> sh);
            }
            if (u2 < SLICE) {
                unsigned sh = (u2 & 1) * 16;
                rank16[e0 + 2] = (ushort)(atomicAdd(&bins[u2 >> 1], 1u << sh) >> sh);
            }
            if (u3 < SLICE) {
                unsigned sh = (u3 & 1) * 16;
                rank16[e0 + 3] = (ushort)(atomicAdd(&bins[u3 >> 1], 1u << sh) >> sh);
            }
        }
    } else {
        for (int i = threadIdx.x; i < CHUNK_E / 4; i += 1024) {
            int4 v = ep4[i];
            unsigned u0 = (unsigned)(v.x - s0);
            unsigned u1 = (unsigned)(v.y - s0);
            unsigned u2 = (unsigned)(v.z - s0);
            unsigned u3 = (unsigned)(v.w - s0);
            if (u0 < SLICE) atomicAdd(&bins[u0 >> 1], 1u << ((u0 & 1) * 16));
            if (u1 < SLICE) atomicAdd(&bins[u1 >> 1], 1u << ((u1 & 1) * 16));
            if (u2 < SLICE) atomicAdd(&bins[u2 >> 1], 1u << ((u2 & 1) * 16));
            if (u3 < SLICE) atomicAdd(&bins[u3 >> 1], 1u << ((u3 & 1) * 16));
        }
    }
    __syncthreads();

    unsigned* pp = (unsigned*)((isdst ? p_in16 : p_out16) + (size_t)ci * N_NODES + s0);
    for (int i = threadIdx.x; i < SLICE_W; i += 1024) pp[i] = bins[i];
}

// ---------------------------------------------------------------------------
// Kernel 2: per-node: nsrc = rsqrt(max(deg_out,1)); exclusive prefix of
// p_in16 over chunks (in place) -> deg_in.
// ---------------------------------------------------------------------------
__global__ __launch_bounds__(256)
void prefix_kernel(const ushort* __restrict__ p_out16, ushort* __restrict__ p_in16,
                   float* __restrict__ nsrc, unsigned* __restrict__ deg_in) {
    int n = blockIdx.x * 256 + threadIdx.x;
    if (n >= N_NODES) return;
    unsigned so = 0;
    #pragma unroll
    for (int c = 0; c < NCHUNK; ++c) so += p_out16[(size_t)c * N_NODES + n];
    nsrc[n] = rsqrtf(fmaxf((float)so, 1.f));
    unsigned run = 0;
    #pragma unroll
    for (int c = 0; c < NCHUNK; ++c) {
        unsigned t = p_in16[(size_t)c * N_NODES + n];
        p_in16[(size_t)c * N_NODES + n] = (ushort)run;
        run += t;
    }
    deg_in[n] = run;
}

// ---------------------------------------------------------------------------
// Kernel 3: single-block exclusive scan, 8 elems/thread (13 outer iters)
// ---------------------------------------------------------------------------
__global__ __launch_bounds__(1024)
void scan_kernel(const unsigned* __restrict__ deg_in, unsigned* __restrict__ row_ptr) {
    __shared__ unsigned wsum[16];
    __shared__ unsigned carry_s;
    if (threadIdx.x == 0) carry_s = 0;
    __syncthreads();
    const int lane = threadIdx.x & 63;
    const int wid  = threadIdx.x >> 6;
    for (int base = 0; base < N_NODES; base += 8192) {
        int i0 = base + threadIdx.x * 8;
        unsigned d[8];
        #pragma unroll
        for (int k = 0; k < 8; ++k) d[k] = 0;
        if (i0 < N_NODES) {   // N_NODES % 8 == 0 -> octet fully in-range
            uint4 v0 = *(const uint4*)(deg_in + i0);
            uint4 v1 = *(const uint4*)(deg_in + i0 + 4);
            d[0] = v0.x; d[1] = v0.y; d[2] = v0.z; d[3] = v0.w;
            d[4] = v1.x; d[5] = v1.y; d[6] = v1.z; d[7] = v1.w;
        }
        unsigned t = 0;
        #pragma unroll
        for (int k = 0; k < 8; ++k) t += d[k];
        unsigned x = t;
        #pragma unroll
        for (int dd = 1; dd < 64; dd <<= 1) {
            unsigned tt = __shfl_up(x, dd, 64);
            if (lane >= dd) x += tt;
        }
        if (lane == 63) wsum[wid] = x;
        __syncthreads();
        if (threadIdx.x == 0) {
            unsigned run = carry_s;
            #pragma unroll
            for (int w = 0; w < 16; ++w) { unsigned tmp = wsum[w]; wsum[w] = run; run += tmp; }
            carry_s = run;
        }
        __syncthreads();
        if (i0 < N_NODES) {
            unsigned bprefix = wsum[wid] + (x - t);
            unsigned rp[8];
            unsigned run = bprefix;
            #pragma unroll
            for (int k = 0; k < 8; ++k) { rp[k] = run; run += d[k]; }
            *(uint4*)(row_ptr + i0)     = make_uint4(rp[0], rp[1], rp[2], rp[3]);
            *(uint4*)(row_ptr + i0 + 4) = make_uint4(rp[4], rp[5], rp[6], rp[7]);
        }
        __syncthreads();
    }
    if (threadIdx.x == 0) row_ptr[N_NODES] = carry_s;
}

// ---------------------------------------------------------------------------
// Kernel 4: atomic-free CSR fill via chunk-prefix + within-chunk rank
// ---------------------------------------------------------------------------
__global__ __launch_bounds__(256)
void fill_kernel(const int* __restrict__ src, const int* __restrict__ dst,
                 const unsigned* __restrict__ row_ptr, const ushort* __restrict__ p_in16,
                 const ushort* __restrict__ rank16, unsigned* __restrict__ edge_src) {
    int e = blockIdx.x * 256 + threadIdx.x;   // grid exact
    int d = dst[e];
    int c = e / CHUNK_E;
    unsigned pos = row_ptr[d] + (unsigned)p_in16[(size_t)c * N_NODES + d]
                 + (unsigned)rank16[e];
    edge_src[pos] = (unsigned)src[e];
}

// ---------------------------------------------------------------------------
// Kernel 5: row-per-wave gather SpMM over bf16 featb, scale by nsrc[s] -> aggb
// (proven full-wave, 8-deep-unroll structure)
// ---------------------------------------------------------------------------
__global__ __launch_bounds__(256)
void spmm_kernel(const ushort* __restrict__ featb, const float* __restrict__ nsrc,
                 const unsigned* __restrict__ row_ptr, const unsigned* __restrict__ edge_src,
                 unsigned* __restrict__ aggb_u32) {
    int gw = (blockIdx.x * 256 + threadIdx.x) >> 6;
    int lane = threadIdx.x & 63;
    if (gw >= N_NODES) return;
    unsigned beg = row_ptr[gw], end = row_ptr[gw + 1];
    float a0 = 0.f, a1 = 0.f;
    unsigned e = beg;
    for (; e + 8 <= end; e += 8) {
        unsigned s[8];
        #pragma unroll
        for (int q = 0; q < 8; ++q) s[q] = edge_src[e + q];
        float ns[8];
        #pragma unroll
        for (int q = 0; q < 8; ++q) ns[q] = nsrc[s[q]];
        unsigned v[8];
        #pragma unroll
        for (int q = 0; q < 8; ++q)
            v[q] = *(const unsigned*)(featb + (size_t)s[q] * IN_DIM + 2 * lane);
        #pragma unroll
        for (int q = 0; q < 8; ++q) {
            a0 = fmaf(bf2f_lo(v[q]), ns[q], a0);
            a1 = fmaf(bf2f_hi(v[q]), ns[q], a1);
        }
    }
    for (; e < end; ++e) {
        unsigned s = edge_src[e];
        float ns = nsrc[s];
        unsigned v = *(const unsigned*)(featb + (size_t)s * IN_DIM + 2 * lane);
        a0 = fmaf(bf2f_lo(v), ns, a0); a1 = fmaf(bf2f_hi(v), ns, a1);
    }
    float nd = rsqrtf(fmaxf((float)(end - beg), 1.0f));
    unsigned lo = (unsigned)(ushort)f2bf(a0 * nd);
    unsigned hi = (unsigned)(ushort)f2bf(a1 * nd);
    aggb_u32[(size_t)gw * (IN_DIM / 2) + lane] = lo | (hi << 16);
}

// ---------------------------------------------------------------------------
// Kernel 6: FUSED GEMM1 + LN + ReLU + GEMM2 -> out, v8 (32-row tiles,
// occupancy-pinned, launch_bounds(256,4)) — unchanged.
// ---------------------------------------------------------------------------
__global__ __launch_bounds__(256, 4)
void gemm_fused_kernel(const ushort* __restrict__ aggb, const ushort* __restrict__ featb,
                       const ushort* __restrict__ Wfrag, const ushort* __restrict__ sWfrag,
                       const float4* __restrict__ params, float* __restrict__ out) {
    __shared__ float2 red[4][32];      // [col-quarter][row-in-tile]: (s1,s2)
    const int tid = threadIdx.x;
    const int lane = tid & 63;
    const int h = tid >> 6;            // col-quarter 0..3
    const int c = lane & 15, g = lane >> 4;
    const int r0 = blockIdx.x * 32;    // tile base row
    const int n0 = h * 4;

    bf16x8 A[2][4];
    #pragma unroll
    for (int rg = 0; rg < 2; ++rg)
        #pragma unroll
        for (int ks = 0; ks < 4; ++ks)
            A[rg][ks] = *(const bf16x8*)(aggb + (size_t)(r0 + rg * 16 + c) * IN_DIM
                                         + ks * 32 + g * 8);

    f32x4 acc[2][4];
    #pragma unroll
    for (int i = 0; i < 4; ++i) {
        float bb = params[(n0 + i) * 16 + c].x;
        acc[0][i] = (f32x4){bb, bb, bb, bb};
        acc[1][i] = (f32x4){bb, bb, bb, bb};
        #pragma unroll
        for (int ks = 0; ks < 4; ++ks) {
            bf16x8 b = *(const bf16x8*)(Wfrag + (((n0 + i) * 4 + ks) * 64 + lane) * 8);
            acc[0][i] = __builtin_amdgcn_mfma_f32_16x16x32_bf16(A[0][ks], b, acc[0][i], 0, 0, 0);
            acc[1][i] = __builtin_amdgcn_mfma_f32_16x16x32_bf16(A[1][ks], b, acc[1][i], 0, 0, 0);
        }
    }

    #pragma unroll
    for (int rg = 0; rg < 2; ++rg)
        #pragma unroll
        for (int ks = 0; ks < 4; ++ks)
            A[rg][ks] = *(const bf16x8*)(featb + (size_t)(r0 + rg * 16 + c) * IN_DIM
                                         + ks * 32 + g * 8);

    {
        float s1[2][4], s2[2][4];
        #pragma unroll
        for (int rg = 0; rg < 2; ++rg)
            #pragma unroll
            for (int j = 0; j < 4; ++j) { s1[rg][j] = 0.f; s2[rg][j] = 0.f; }
        #pragma unroll
        for (int rg = 0; rg < 2; ++rg)
            #pragma unroll
            for (int i = 0; i < 4; ++i)
                #pragma unroll
                for (int j = 0; j < 4; ++j) {
                    s1[rg][j] += acc[rg][i][j];
                    s2[rg][j] = fmaf(acc[rg][i][j], acc[rg][i][j], s2[rg][j]);
                }
        #pragma unroll
        for (int m = 1; m <= 8; m <<= 1)
            #pragma unroll
            for (int rg = 0; rg < 2; ++rg)
                #pragma unroll
                for (int j = 0; j < 4; ++j) {
                    s1[rg][j] += __shfl_xor(s1[rg][j], m, 64);
                    s2[rg][j] += __shfl_xor(s2[rg][j], m, 64);
                }
        if (c == 0) {
            #pragma unroll
            for (int rg = 0; rg < 2; ++rg)
                #pragma unroll
                for (int j = 0; j < 4; ++j)
                    red[h][rg * 16 + g * 4 + j] = make_float2(s1[rg][j], s2[rg][j]);
        }
    }
    __syncthreads();

    float mu[2][4], rstd[2][4];
    #pragma unroll
    for (int rg = 0; rg < 2; ++rg)
        #pragma unroll
        for (int j = 0; j < 4; ++j) {
            int row = rg * 16 + g * 4 + j;
            float2 p0 = red[0][row];
            float2 p1 = red[1][row];
            float2 p2 = red[2][row];
            float2 p3 = red[3][row];
            float t1 = (p0.x + p1.x) + (p2.x + p3.x);
            float t2 = (p0.y + p1.y) + (p2.y + p3.y);
            mu[rg][j] = t1 * (1.f / HID_DIM);
            float var = t2 * (1.f / HID_DIM) - mu[rg][j] * mu[rg][j];
            rstd[rg][j] = rsqrtf(var + LN_EPS);
        }

    #pragma unroll
    for (int i = 0; i < 4; ++i) {
        float4 p = params[(n0 + i) * 16 + c];   // {b, gamma, beta, skipb}
        #pragma unroll
        for (int rg = 0; rg < 2; ++rg)
            #pragma unroll
            for (int j = 0; j < 4; ++j)
                acc[rg][i][j] = fmaxf(fmaf((acc[rg][i][j] - mu[rg][j]) * rstd[rg][j],
                                           p.y, p.z), 0.f) + p.w;
    }

    #pragma unroll
    for (int i = 0; i < 4; ++i) {
        #pragma unroll
        for (int ks = 0; ks < 4; ++ks) {
            bf16x8 b = *(const bf16x8*)(sWfrag + (((n0 + i) * 4 + ks) * 64 + lane) * 8);
            acc[0][i] = __builtin_amdgcn_mfma_f32_16x16x32_bf16(A[0][ks], b, acc[0][i], 0, 0, 0);
            acc[1][i] = __builtin_amdgcn_mfma_f32_16x16x32_bf16(A[1][ks], b, acc[1][i], 0, 0, 0);
        }
    }

    #pragma unroll
    for (int rg = 0; rg < 2; ++rg)
        #pragma unroll
        for (int i = 0; i < 4; ++i)
            #pragma unroll
            for (int j = 0; j < 4; ++j)
                out[(size_t)(r0 + rg * 16 + g * 4 + j) * HID_DIM + (n0 + i) * 16 + c]
                    = acc[rg][i][j];
}

// ---------------------------------------------------------------------------
extern "C" void kernel_launch(void* const* d_in, const int* in_sizes, int n_in,
                              void* d_out, int out_size, void* d_ws, size_t ws_size,
                              hipStream_t stream) {
    const float* feat  = (const float*)d_in[0];
    const int*   src   = (const int*)d_in[1];
    const int*   dst   = (const int*)d_in[2];
    const float* W     = (const float*)d_in[3];
    const float* bvec  = (const float*)d_in[4];
    const float* gamma = (const float*)d_in[5];
    const float* beta  = (const float*)d_in[6];
    const float* skipW = (const float*)d_in[7];
    const float* skipb = (const float*)d_in[8];
    float* out = (float*)d_out;

    // workspace, peak ≈ 70 MB. NOTE: featb no longer aliases p_out16 (featb
    // is now written in the SAME kernel that writes p_out16) — featb gets its
    // own segment; p_out16 moves after it.
    char* ws = (char*)d_ws;
    ushort*   Wfrag    = (ushort*)ws;                               // 64 KB
    ushort*   sWfrag   = Wfrag + 32768;                             // 64 KB
    float4*   params   = (float4*)(sWfrag + 32768);                 // 4 KB
    ushort*   aggb     = (ushort*)(params + 256);                   // 25.6 MB
    ushort*   featb    = aggb + (size_t)N_NODES * IN_DIM;           // 25.6 MB
    unsigned* edge_src = (unsigned*)(featb + (size_t)N_NODES * IN_DIM); // 6.4 MB
    ushort*   rank16   = (ushort*)(edge_src + N_EDGES);             // 3.2 MB
    ushort*   p_in16   = rank16 + N_EDGES;                          // 6.4 MB
    ushort*   p_out16  = p_in16 + (size_t)NCHUNK * N_NODES;         // 6.4 MB
    float*    nsrc     = (float*)(p_out16 + (size_t)NCHUNK * N_NODES); // 400 KB
    unsigned* deg_in   = (unsigned*)(nsrc + N_NODES);               // 400 KB
    unsigned* row_ptr  = deg_in + N_NODES;                          // 400 KB + pad

    hist_kernel<<<2 * HBLK + WCVT_BLKS + FCVT_BLKS, 1024, 0, stream>>>(
        src, dst, p_out16, p_in16, rank16,
        W, skipW, bvec, gamma, beta, skipb, Wfrag, sWfrag, params, feat, featb);

    prefix_kernel<<<(N_NODES + 255) / 256, 256, 0, stream>>>(p_out16, p_in16, nsrc, deg_in);

    scan_kernel<<<1, 1024, 0, stream>>>(deg_in, row_ptr);

    fill_kernel<<<EDGE_BLOCKS, 256, 0, stream>>>(src, dst, row_ptr, p_in16, rank16, edge_src);

    spmm_kernel<<<(N_NODES * 64 + 255) / 256, 256, 0, stream>>>(featb, nsrc, row_ptr,
                                                                edge_src, (unsigned*)aggb);

    gemm_fused_kernel<<<NT32, 256, 0, stream>>>(
        aggb, featb, Wfrag, sWfrag, params, out);
}